// Round 2
// baseline (396.520 us; speedup 1.0000x reference)
//
#include <hip/hip_runtime.h>

// ---------------------------------------------------------------------------
// Builder: compute C[i][p] (4 x 81 floats), the trig-monomial coefficients:
//   ev_i(a0..a3) = sum_{t in {0,1,2}^4} C_i[t] * prod_w f_{t_w}(a_w),
//   f_0 = 1, f_1 = cos a, f_2 = sin a,  p = ((t0*3+t1)*9 + (t2*3+t3)).
// Derivation: ev_i = s^T M_i s, M_i = Re(V^dag Z_i V),
//   s = (x)_w (cos a_w/2, sin a_w/2),  v v^T = (B0 + cos a B1 + sin a B2)/2
//   with B0=I, B1=Z, B2=X  ->  C_i[t] = (1/16) <M_i, B_t0 (x) ... (x) B_t3>.
// Wire w <-> bit (3-w) of flattened index (wire 0 = MSB).
// ---------------------------------------------------------------------------
__global__ void build_C_kernel(const float* __restrict__ w, float* __restrict__ Cout) {
    __shared__ float Vr[16][17];
    __shared__ float Vi[16][17];
    __shared__ float Msh[4][16][16];
    int t = threadIdx.x;
    if (t < 16) {
        float vr[16], vi[16];
        #pragma unroll
        for (int m = 0; m < 16; ++m) { vr[m] = (m == t) ? 1.f : 0.f; vi[m] = 0.f; }
        for (int L = 0; L < 3; ++L) {
            for (int q = 0; q < 4; ++q) {
                float phi = w[L * 12 + q * 3 + 0];
                float th  = w[L * 12 + q * 3 + 1];
                float om  = w[L * 12 + q * 3 + 2];
                float ct = cosf(0.5f * th), st = sinf(0.5f * th);
                float a  = 0.5f * (phi + om), d = 0.5f * (phi - om);
                float ca = cosf(a), sa = sinf(a), cd = cosf(d), sd = sinf(d);
                // Rot = RZ(om) RY(th) RZ(phi)
                float u00r =  ct * ca, u00i = -ct * sa;
                float u01r = -st * cd, u01i = -st * sd;
                float u10r =  st * cd, u10i = -st * sd;
                float u11r =  ct * ca, u11i =  ct * sa;
                int mask = 8 >> q;
                #pragma unroll
                for (int idx = 0; idx < 16; ++idx) {
                    if (idx & mask) continue;
                    int hi = idx | mask;
                    float ar = vr[idx], ai = vi[idx];
                    float br = vr[hi],  bi = vi[hi];
                    vr[idx] = u00r * ar - u00i * ai + u01r * br - u01i * bi;
                    vi[idx] = u00r * ai + u00i * ar + u01r * bi + u01i * br;
                    vr[hi]  = u10r * ar - u10i * ai + u11r * br - u11i * bi;
                    vi[hi]  = u10r * ai + u10i * ar + u11r * bi + u11i * br;
                }
            }
            #pragma unroll
            for (int q = 0; q < 4; ++q) {
                int cm = 8 >> q;
                int tm = 8 >> ((q + 1) & 3);
                #pragma unroll
                for (int idx = 0; idx < 16; ++idx) {
                    if ((idx & cm) && !(idx & tm)) {
                        int o = idx | tm;
                        float tr = vr[idx], ti = vi[idx];
                        vr[idx] = vr[o]; vi[idx] = vi[o];
                        vr[o] = tr;      vi[o] = ti;
                    }
                }
            }
        }
        #pragma unroll
        for (int m = 0; m < 16; ++m) { Vr[m][t] = vr[m]; Vi[m][t] = vi[m]; }
    }
    __syncthreads();
    // M_i[j][k] = sum_m z_i(m) * (Vr[m][j]Vr[m][k] + Vi[m][j]Vi[m][k])
    for (int e = t; e < 1024; e += 64) {
        int i = e >> 8, j = (e >> 4) & 15, k = e & 15;
        float acc = 0.f;
        #pragma unroll
        for (int m = 0; m < 16; ++m) {
            float term = Vr[m][j] * Vr[m][k] + Vi[m][j] * Vi[m][k];
            acc += ((m >> (3 - i)) & 1) ? -term : term;
        }
        Msh[i][j][k] = acc;
    }
    __syncthreads();
    // C[i][p] = (1/16) sum_{j,k} M_i[j][k] * prod_w B_{t_w}[j_w][k_w]
    for (int e = t; e < 324; e += 64) {
        int i = e / 81, p = e % 81;
        int tw[4] = { p / 27, (p / 9) % 3, (p / 3) % 3, p % 3 };
        float acc = 0.f;
        for (int j = 0; j < 16; ++j) {
            for (int k = 0; k < 16; ++k) {
                float f = 1.f;
                #pragma unroll
                for (int wq = 0; wq < 4; ++wq) {
                    int jw = (j >> (3 - wq)) & 1;
                    int kw = (k >> (3 - wq)) & 1;
                    int tt = tw[wq];
                    float fac;
                    if (tt == 0)      fac = (jw == kw) ? 1.f : 0.f;
                    else if (tt == 1) fac = (jw == kw) ? (jw ? -1.f : 1.f) : 0.f;
                    else              fac = (jw != kw) ? 1.f : 0.f;
                    f *= fac;
                }
                acc += Msh[i][j][k] * f;
            }
        }
        Cout[e] = acc * 0.0625f;
    }
}

// ---------------------------------------------------------------------------
// Fused main kernel: 256 threads / block, 256 rows / block, 1 row / thread.
// All shared operands (W_in, b_in, C) are wave-uniform -> scalar loads;
// x row lives in registers; only LDS use is the 4 KB epilogue exchange.
// ---------------------------------------------------------------------------
__global__ __launch_bounds__(256) void qffn_kernel(
        const float* __restrict__ x,
        const float* __restrict__ W_in,
        const float* __restrict__ b_in,
        const float* __restrict__ W_out,
        const float* __restrict__ b_out,
        const float* __restrict__ Cg,
        float* __restrict__ out,
        int nrows) {
    __shared__ __align__(16) float qs[256][4];
    const int t = threadIdx.x;
    const long rbase = (long)blockIdx.x * 256;

    long r = rbase + t;
    if (r >= nrows) r = nrows - 1;

    // ---- load this thread's x row (16 x float4, L1-window friendly) ----
    const float4* xr = (const float4*)(x + r * 64);
    float4 xv[16];
    #pragma unroll
    for (int k = 0; k < 16; ++k) xv[k] = xr[k];

    // ---- projection: acc_i = b_i + sum_j x[j] * W_in[i][j] (W via s_load) ----
    float acc0 = b_in[0], acc1 = b_in[1], acc2 = b_in[2], acc3 = b_in[3];
    #pragma unroll
    for (int k = 0; k < 16; ++k) {
        const float xk0 = xv[k].x, xk1 = xv[k].y, xk2 = xv[k].z, xk3 = xv[k].w;
        acc0 += xk0 * W_in[0 * 64 + k * 4 + 0] + xk1 * W_in[0 * 64 + k * 4 + 1]
              + xk2 * W_in[0 * 64 + k * 4 + 2] + xk3 * W_in[0 * 64 + k * 4 + 3];
        acc1 += xk0 * W_in[1 * 64 + k * 4 + 0] + xk1 * W_in[1 * 64 + k * 4 + 1]
              + xk2 * W_in[1 * 64 + k * 4 + 2] + xk3 * W_in[1 * 64 + k * 4 + 3];
        acc2 += xk0 * W_in[2 * 64 + k * 4 + 0] + xk1 * W_in[2 * 64 + k * 4 + 1]
              + xk2 * W_in[2 * 64 + k * 4 + 2] + xk3 * W_in[2 * 64 + k * 4 + 3];
        acc3 += xk0 * W_in[3 * 64 + k * 4 + 0] + xk1 * W_in[3 * 64 + k * 4 + 1]
              + xk2 * W_in[3 * 64 + k * 4 + 2] + xk3 * W_in[3 * 64 + k * 4 + 3];
    }

    // ---- tanh -> angle a = pi*tanh(u) -> cos a, sin a ----
    const float PI = 3.14159265358979323846f;
    float cs[4], sn[4];
    {
        float u[4] = { acc0, acc1, acc2, acc3 };
        #pragma unroll
        for (int i = 0; i < 4; ++i) {
            float e  = __expf(2.f * u[i]);
            float th = 1.f - 2.f / (e + 1.f);
            float a  = PI * th;
            cs[i] = __cosf(a);
            sn[i] = __sinf(a);
        }
    }

    // ---- trig-monomial bases (wires 0,1 -> F; wires 2,3 -> G) ----
    float F[9] = { 1.f,   cs[1],        sn[1],
                   cs[0], cs[0]*cs[1],  cs[0]*sn[1],
                   sn[0], sn[0]*cs[1],  sn[0]*sn[1] };
    float G[9] = { 1.f,   cs[3],        sn[3],
                   cs[2], cs[2]*cs[3],  cs[2]*sn[3],
                   sn[2], sn[2]*cs[3],  sn[2]*sn[3] };

    // ---- ev_i = F^T C_i G (C via s_load; 1 SGPR operand per FMA) ----
    float ev[4];
    #pragma unroll
    for (int i = 0; i < 4; ++i) {
        float a = 0.f;
        #pragma unroll
        for (int p = 0; p < 9; ++p) {
            float h = 0.f;
            #pragma unroll
            for (int q = 0; q < 9; ++q)
                h += Cg[i * 81 + p * 9 + q] * G[q];
            a += F[p] * h;
        }
        ev[i] = a;
    }

    qs[t][0] = ev[0]; qs[t][1] = ev[1]; qs[t][2] = ev[2]; qs[t][3] = ev[3];
    __syncthreads();

    // ---- output projection, cooperative: thread owns 4 contiguous cols ----
    const int cg = (t & 15) << 2;   // column group base
    const int r0 = t >> 4;          // row phase 0..15
    const float4 wo0 = *(const float4*)(W_out + (cg + 0) * 4);
    const float4 wo1 = *(const float4*)(W_out + (cg + 1) * 4);
    const float4 wo2 = *(const float4*)(W_out + (cg + 2) * 4);
    const float4 wo3 = *(const float4*)(W_out + (cg + 3) * 4);
    const float4 bo  = *(const float4*)(b_out + cg);
    #pragma unroll
    for (int k = 0; k < 16; ++k) {
        int rr = k * 16 + r0;
        float4 q = *(const float4*)&qs[rr][0];
        float4 o;
        o.x = bo.x + q.x * wo0.x + q.y * wo0.y + q.z * wo0.z + q.w * wo0.w;
        o.y = bo.y + q.x * wo1.x + q.y * wo1.y + q.z * wo1.z + q.w * wo1.w;
        o.z = bo.z + q.x * wo2.x + q.y * wo2.y + q.z * wo2.z + q.w * wo2.w;
        o.w = bo.w + q.x * wo3.x + q.y * wo3.y + q.z * wo3.z + q.w * wo3.w;
        long gr = rbase + rr;
        if (gr < nrows) *(float4*)(out + gr * 64 + cg) = o;
    }
}

extern "C" void kernel_launch(void* const* d_in, const int* in_sizes, int n_in,
                              void* d_out, int out_size, void* d_ws, size_t ws_size,
                              hipStream_t stream) {
    const float* x       = (const float*)d_in[0];
    const float* W_in    = (const float*)d_in[1];
    const float* b_in    = (const float*)d_in[2];
    const float* weights = (const float*)d_in[3];
    const float* W_out   = (const float*)d_in[4];
    const float* b_out   = (const float*)d_in[5];
    float* out = (float*)d_out;
    float* C   = (float*)d_ws;   // 4*81 floats

    int nrows = in_sizes[0] / 64;           // x is (N, 64)
    int nblk  = (nrows + 255) / 256;

    hipLaunchKernelGGL(build_C_kernel, dim3(1), dim3(64), 0, stream, weights, C);
    hipLaunchKernelGGL(qffn_kernel, dim3(nblk), dim3(256), 0, stream,
                       x, W_in, b_in, W_out, b_out, C, out, nrows);
}

// Round 3
// 51.289 us; speedup vs baseline: 7.7310x; 7.7310x over previous
//
#include <hip/hip_runtime.h>

// ---------------------------------------------------------------------------
// Builder: compute C[i][p] (4 x 81 floats), the trig-monomial coefficients:
//   ev_i(a0..a3) = sum_{t in {0,1,2}^4} C_i[t] * prod_w f_{t_w}(a_w),
//   f_0 = 1, f_1 = cos a, f_2 = sin a,  p = ((t0*3+t1)*9 + (t2*3+t3)).
// ev_i = s^T M_i s with M_i = Re(V^dag Z_i V); v v^T = (I + cos a Z + sin a X)/2
// => C_i[t] = (1/16) <M_i, B_t0 (x) ... (x) B_t3>.
// Pauli-string closed form: the tensor product has one nonzero per row:
//   k = j ^ xmask (X positions), value (-1)^popc(j & zmask) (Z positions)
// => C_i[p] = (1/16) sum_j sign(j) * M_i[j][j ^ xmask]   (16 terms, branch-free).
// Wire w <-> bit (3-w) of flattened index (wire 0 = MSB).
// ---------------------------------------------------------------------------
__global__ void build_C_kernel(const float* __restrict__ w, float* __restrict__ Cout) {
    __shared__ float Vr[16][17];
    __shared__ float Vi[16][17];
    __shared__ float Msh[4][16][16];
    int t = threadIdx.x;   // 256 threads
    if (t < 16) {
        float vr[16], vi[16];
        #pragma unroll
        for (int m = 0; m < 16; ++m) { vr[m] = (m == t) ? 1.f : 0.f; vi[m] = 0.f; }
        for (int L = 0; L < 3; ++L) {
            for (int q = 0; q < 4; ++q) {
                float phi = w[L * 12 + q * 3 + 0];
                float th  = w[L * 12 + q * 3 + 1];
                float om  = w[L * 12 + q * 3 + 2];
                float ct = cosf(0.5f * th), st = sinf(0.5f * th);
                float a  = 0.5f * (phi + om), d = 0.5f * (phi - om);
                float ca = cosf(a), sa = sinf(a), cd = cosf(d), sd = sinf(d);
                // Rot = RZ(om) RY(th) RZ(phi)
                float u00r =  ct * ca, u00i = -ct * sa;
                float u01r = -st * cd, u01i = -st * sd;
                float u10r =  st * cd, u10i = -st * sd;
                float u11r =  ct * ca, u11i =  ct * sa;
                int mask = 8 >> q;
                #pragma unroll
                for (int idx = 0; idx < 16; ++idx) {
                    if (idx & mask) continue;
                    int hi = idx | mask;
                    float ar = vr[idx], ai = vi[idx];
                    float br = vr[hi],  bi = vi[hi];
                    vr[idx] = u00r * ar - u00i * ai + u01r * br - u01i * bi;
                    vi[idx] = u00r * ai + u00i * ar + u01r * bi + u01i * br;
                    vr[hi]  = u10r * ar - u10i * ai + u11r * br - u11i * bi;
                    vi[hi]  = u10r * ai + u10i * ar + u11r * bi + u11i * br;
                }
            }
            #pragma unroll
            for (int q = 0; q < 4; ++q) {
                int cm = 8 >> q;
                int tm = 8 >> ((q + 1) & 3);
                #pragma unroll
                for (int idx = 0; idx < 16; ++idx) {
                    if ((idx & cm) && !(idx & tm)) {
                        int o = idx | tm;
                        float tr = vr[idx], ti = vi[idx];
                        vr[idx] = vr[o]; vi[idx] = vi[o];
                        vr[o] = tr;      vi[o] = ti;
                    }
                }
            }
        }
        #pragma unroll
        for (int m = 0; m < 16; ++m) { Vr[m][t] = vr[m]; Vi[m][t] = vi[m]; }
    }
    __syncthreads();
    // M_i[j][k] = sum_m z_i(m) * (Vr[m][j]Vr[m][k] + Vi[m][j]Vi[m][k])
    for (int e = t; e < 1024; e += 256) {
        int i = e >> 8, j = (e >> 4) & 15, k = e & 15;
        float acc = 0.f;
        #pragma unroll
        for (int m = 0; m < 16; ++m) {
            float term = Vr[m][j] * Vr[m][k] + Vi[m][j] * Vi[m][k];
            acc += ((m >> (3 - i)) & 1) ? -term : term;
        }
        Msh[i][j][k] = acc;
    }
    __syncthreads();
    // Branch-free Pauli projection: 16 signed LDS reads per element.
    for (int e = t; e < 324; e += 256) {
        int i = e / 81, p = e % 81;
        int t0 = p / 27, t1 = (p / 9) % 3, t2 = (p / 3) % 3, t3 = p % 3;
        int xm = ((t0 == 2) << 3) | ((t1 == 2) << 2) | ((t2 == 2) << 1) | (int)(t3 == 2);
        int zm = ((t0 == 1) << 3) | ((t1 == 1) << 2) | ((t2 == 1) << 1) | (int)(t3 == 1);
        float acc = 0.f;
        #pragma unroll
        for (int j = 0; j < 16; ++j) {
            float v = Msh[i][j][j ^ xm];
            acc += (__popc(j & zm) & 1) ? -v : v;
        }
        Cout[e] = acc * 0.0625f;
    }
}

// ---------------------------------------------------------------------------
// Fused main kernel: 256 threads / block, 256 rows / block, 1 row / thread.
// All shared operands (W_in, b_in, C) are wave-uniform -> scalar loads;
// x row lives in registers; only LDS use is the 4 KB epilogue exchange.
// (Unchanged from R1 — it measured 14.6 us, matching prediction.)
// ---------------------------------------------------------------------------
__global__ __launch_bounds__(256) void qffn_kernel(
        const float* __restrict__ x,
        const float* __restrict__ W_in,
        const float* __restrict__ b_in,
        const float* __restrict__ W_out,
        const float* __restrict__ b_out,
        const float* __restrict__ Cg,
        float* __restrict__ out,
        int nrows) {
    __shared__ __align__(16) float qs[256][4];
    const int t = threadIdx.x;
    const long rbase = (long)blockIdx.x * 256;

    long r = rbase + t;
    if (r >= nrows) r = nrows - 1;

    // ---- load this thread's x row (16 x float4) ----
    const float4* xr = (const float4*)(x + r * 64);
    float4 xv[16];
    #pragma unroll
    for (int k = 0; k < 16; ++k) xv[k] = xr[k];

    // ---- projection: acc_i = b_i + sum_j x[j] * W_in[i][j] (W via s_load) ----
    float acc0 = b_in[0], acc1 = b_in[1], acc2 = b_in[2], acc3 = b_in[3];
    #pragma unroll
    for (int k = 0; k < 16; ++k) {
        const float xk0 = xv[k].x, xk1 = xv[k].y, xk2 = xv[k].z, xk3 = xv[k].w;
        acc0 += xk0 * W_in[0 * 64 + k * 4 + 0] + xk1 * W_in[0 * 64 + k * 4 + 1]
              + xk2 * W_in[0 * 64 + k * 4 + 2] + xk3 * W_in[0 * 64 + k * 4 + 3];
        acc1 += xk0 * W_in[1 * 64 + k * 4 + 0] + xk1 * W_in[1 * 64 + k * 4 + 1]
              + xk2 * W_in[1 * 64 + k * 4 + 2] + xk3 * W_in[1 * 64 + k * 4 + 3];
        acc2 += xk0 * W_in[2 * 64 + k * 4 + 0] + xk1 * W_in[2 * 64 + k * 4 + 1]
              + xk2 * W_in[2 * 64 + k * 4 + 2] + xk3 * W_in[2 * 64 + k * 4 + 3];
        acc3 += xk0 * W_in[3 * 64 + k * 4 + 0] + xk1 * W_in[3 * 64 + k * 4 + 1]
              + xk2 * W_in[3 * 64 + k * 4 + 2] + xk3 * W_in[3 * 64 + k * 4 + 3];
    }

    // ---- tanh -> angle a = pi*tanh(u) -> cos a, sin a ----
    const float PI = 3.14159265358979323846f;
    float cs[4], sn[4];
    {
        float u[4] = { acc0, acc1, acc2, acc3 };
        #pragma unroll
        for (int i = 0; i < 4; ++i) {
            float e  = __expf(2.f * u[i]);
            float th = 1.f - 2.f / (e + 1.f);
            float a  = PI * th;
            cs[i] = __cosf(a);
            sn[i] = __sinf(a);
        }
    }

    // ---- trig-monomial bases (wires 0,1 -> F; wires 2,3 -> G) ----
    float F[9] = { 1.f,   cs[1],        sn[1],
                   cs[0], cs[0]*cs[1],  cs[0]*sn[1],
                   sn[0], sn[0]*cs[1],  sn[0]*sn[1] };
    float G[9] = { 1.f,   cs[3],        sn[3],
                   cs[2], cs[2]*cs[3],  cs[2]*sn[3],
                   sn[2], sn[2]*cs[3],  sn[2]*sn[3] };

    // ---- ev_i = F^T C_i G (C via s_load; 1 SGPR operand per FMA) ----
    float ev[4];
    #pragma unroll
    for (int i = 0; i < 4; ++i) {
        float a = 0.f;
        #pragma unroll
        for (int p = 0; p < 9; ++p) {
            float h = 0.f;
            #pragma unroll
            for (int q = 0; q < 9; ++q)
                h += Cg[i * 81 + p * 9 + q] * G[q];
            a += F[p] * h;
        }
        ev[i] = a;
    }

    qs[t][0] = ev[0]; qs[t][1] = ev[1]; qs[t][2] = ev[2]; qs[t][3] = ev[3];
    __syncthreads();

    // ---- output projection, cooperative: thread owns 4 contiguous cols ----
    const int cg = (t & 15) << 2;   // column group base
    const int r0 = t >> 4;          // row phase 0..15
    const float4 wo0 = *(const float4*)(W_out + (cg + 0) * 4);
    const float4 wo1 = *(const float4*)(W_out + (cg + 1) * 4);
    const float4 wo2 = *(const float4*)(W_out + (cg + 2) * 4);
    const float4 wo3 = *(const float4*)(W_out + (cg + 3) * 4);
    const float4 bo  = *(const float4*)(b_out + cg);
    #pragma unroll
    for (int k = 0; k < 16; ++k) {
        int rr = k * 16 + r0;
        float4 q = *(const float4*)&qs[rr][0];
        float4 o;
        o.x = bo.x + q.x * wo0.x + q.y * wo0.y + q.z * wo0.z + q.w * wo0.w;
        o.y = bo.y + q.x * wo1.x + q.y * wo1.y + q.z * wo1.z + q.w * wo1.w;
        o.z = bo.z + q.x * wo2.x + q.y * wo2.y + q.z * wo2.z + q.w * wo2.w;
        o.w = bo.w + q.x * wo3.x + q.y * wo3.y + q.z * wo3.z + q.w * wo3.w;
        long gr = rbase + rr;
        if (gr < nrows) *(float4*)(out + gr * 64 + cg) = o;
    }
}

extern "C" void kernel_launch(void* const* d_in, const int* in_sizes, int n_in,
                              void* d_out, int out_size, void* d_ws, size_t ws_size,
                              hipStream_t stream) {
    const float* x       = (const float*)d_in[0];
    const float* W_in    = (const float*)d_in[1];
    const float* b_in    = (const float*)d_in[2];
    const float* weights = (const float*)d_in[3];
    const float* W_out   = (const float*)d_in[4];
    const float* b_out   = (const float*)d_in[5];
    float* out = (float*)d_out;
    float* C   = (float*)d_ws;   // 4*81 floats

    int nrows = in_sizes[0] / 64;           // x is (N, 64)
    int nblk  = (nrows + 255) / 256;

    hipLaunchKernelGGL(build_C_kernel, dim3(1), dim3(256), 0, stream, weights, C);
    hipLaunchKernelGGL(qffn_kernel, dim3(nblk), dim3(256), 0, stream,
                       x, W_in, b_in, W_out, b_out, C, out, nrows);
}